// Round 1
// baseline (260.233 us; speedup 1.0000x reference)
//
#include <hip/hip_runtime.h>
#include <hip/hip_bf16.h>

typedef __attribute__((ext_vector_type(8))) short bf16x8;
typedef __attribute__((ext_vector_type(4))) float f32x4;

#define MFMA_16x16x32(a,b,c) __builtin_amdgcn_mfma_f32_16x16x32_bf16((a),(b),(c),0,0,0)

__device__ __forceinline__ unsigned short f2bf(float f){
  unsigned int u = __float_as_uint(f);
  u += 0x7FFFu + ((u >> 16) & 1u);   // RNE
  return (unsigned short)(u >> 16);
}

__device__ __forceinline__ void async16(const void* g, void* l){
  __builtin_amdgcn_global_load_lds((const __attribute__((address_space(1))) void*)g,
                                   (__attribute__((address_space(3))) void*)l,
                                   16, 0, 0);
}

// ---------------- converters ----------------
__global__ __launch_bounds__(256) void convert_x_kernel(const float* __restrict__ x,
                                                        unsigned short* __restrict__ xb, int n4){
  int idx = blockIdx.x*256 + threadIdx.x;
  int stride = gridDim.x*256;
  for (int i = idx; i < n4; i += stride){
    float4 v = reinterpret_cast<const float4*>(x)[i];
    ushort4 o;
    o.x = f2bf(v.x); o.y = f2bf(v.y); o.z = f2bf(v.z); o.w = f2bf(v.w);
    reinterpret_cast<ushort4*>(xb)[i] = o;
  }
}

__global__ __launch_bounds__(256) void prep_weights(const float* __restrict__ Wq,
                                                    const float* __restrict__ Wk,
                                                    const float* __restrict__ Wv,
                                                    const float* __restrict__ Wo,
                                                    unsigned short* __restrict__ WqkvT,
                                                    unsigned short* __restrict__ WoT){
  int idx = blockIdx.x*256 + threadIdx.x;
  int stride = gridDim.x*256;
  const int T1 = 1536*512;
  const int total = T1 + 512*512;
  for (int o = idx; o < total; o += stride){
    if (o < T1){
      int n = o >> 9, k = o & 511;
      const float* W = (n < 512) ? Wq : ((n < 1024) ? Wk : Wv);
      WqkvT[o] = f2bf(W[k*512 + (n & 511)]);
    } else {
      int o2 = o - T1;
      int n = o2 >> 9, k = o2 & 511;
      WoT[o2] = f2bf(Wo[k*512 + n]);
    }
  }
}

// ---------------- GEMM: C[M,N] = A[M,K] * Bt[N,K]^T (+bias) ----------------
template<bool BIAS, bool OUTBF16>
__global__ __launch_bounds__(256) void gemm_bt(const unsigned short* __restrict__ A,
                                               const unsigned short* __restrict__ Bt,
                                               float* __restrict__ Cf, unsigned short* __restrict__ Cb,
                                               const float* __restrict__ bias,
                                               int M, int N, int K, int ldc){
  __shared__ __attribute__((aligned(16))) unsigned short As[128*64];
  __shared__ __attribute__((aligned(16))) unsigned short Bs[128*64];
  const int tid = threadIdx.x;
  const int lane = tid & 63;
  const int w = tid >> 6;
  const int l15 = lane & 15, lhi = lane >> 4;
  const int NB = N >> 7;
  const int bm = blockIdx.x / NB;
  const int bn = blockIdx.x % NB;
  const int wr = w >> 1, wc = w & 1;
  const f32x4 fzero = {0.f,0.f,0.f,0.f};

  f32x4 acc[4][4];
  #pragma unroll
  for (int a=0;a<4;++a)
    #pragma unroll
    for (int b=0;b<4;++b) acc[a][b] = fzero;

  for (int kt = 0; kt < K; kt += 64){
    #pragma unroll
    for (int j=0;j<4;++j){
      int c = (w*4+j)*64 + lane;
      int row = c >> 3;
      int inner = (c & 7) << 4;
      int src = inner ^ ((row & 7) << 4);   // inverse-swizzled source (rule #21)
      async16((const char*)(A + (size_t)(bm*128 + row)*K + kt) + src,
              (char*)As + ((w*4+j) << 10));
    }
    #pragma unroll
    for (int j=0;j<4;++j){
      int c = (w*4+j)*64 + lane;
      int row = c >> 3;
      int inner = (c & 7) << 4;
      int src = inner ^ ((row & 7) << 4);
      async16((const char*)(Bt + (size_t)(bn*128 + row)*K + kt) + src,
              (char*)Bs + ((w*4+j) << 10));
    }
    __syncthreads();
    #pragma unroll
    for (int kk=0;kk<2;++kk){
      bf16x8 af[4], bfr[4];
      #pragma unroll
      for (int mi=0;mi<4;++mi){
        int m = wr*64 + mi*16 + l15;
        int off = m*128 + (((kk<<6) + (lhi<<4)) ^ ((m & 7) << 4));
        af[mi] = *reinterpret_cast<const bf16x8*>((const char*)As + off);
      }
      #pragma unroll
      for (int ni=0;ni<4;++ni){
        int n = wc*64 + ni*16 + l15;
        int off = n*128 + (((kk<<6) + (lhi<<4)) ^ ((n & 7) << 4));
        bfr[ni] = *reinterpret_cast<const bf16x8*>((const char*)Bs + off);
      }
      #pragma unroll
      for (int mi=0;mi<4;++mi)
        #pragma unroll
        for (int ni=0;ni<4;++ni)
          acc[mi][ni] = MFMA_16x16x32(af[mi], bfr[ni], acc[mi][ni]);
    }
    __syncthreads();
  }
  #pragma unroll
  for (int mi=0;mi<4;++mi){
    int r = bm*128 + wr*64 + mi*16 + lhi*4;
    #pragma unroll
    for (int ni=0;ni<4;++ni){
      int cc = bn*128 + wc*64 + ni*16 + l15;
      float bv = 0.f;
      if (BIAS) bv = bias[cc];
      #pragma unroll
      for (int i=0;i<4;++i){
        float v = acc[mi][ni][i] + bv;
        if (OUTBF16) Cb[(size_t)(r+i)*ldc + cc] = f2bf(v);
        else         Cf[(size_t)(r+i)*ldc + cc] = v;
      }
    }
  }
}

// ---------------- attention: per (b,t,h), 64 q-rows per block ----------------
__global__ __launch_bounds__(256) void attn_kernel(const unsigned short* __restrict__ qkv,
                                                   unsigned short* __restrict__ ctx){
  __shared__ __attribute__((aligned(16))) unsigned short Ks[256*64];   // [tok][64], XOR-swizzled
  __shared__ __attribute__((aligned(16))) unsigned short Vst[64*296];  // [d][tok], padded
  __shared__ __attribute__((aligned(16))) unsigned short Ps[4*16*296]; // per-wave P, padded

  const int bid = blockIdx.x;
  const int g = bid >> 2, qc = bid & 3;
  const int h = g & 7, bt = g >> 3;
  const int r0 = bt << 8;
  const int tid = threadIdx.x;
  const int lane = tid & 63, w = tid >> 6;
  const int l15 = lane & 15, lhi = lane >> 4;
  const char* qkvB = (const char*)qkv;
  const f32x4 fzero = {0.f,0.f,0.f,0.f};

  // stage K (swizzled source -> linear LDS dest)
  #pragma unroll
  for (int j=0;j<8;++j){
    int c = (w*8+j)*64 + lane;
    int row = c >> 3;
    int inner = (c & 7) << 4;
    int src = inner ^ ((row & 7) << 4);
    async16(qkvB + ((size_t)(r0 + row)*1536 + 512 + h*64)*2 + src,
            (char*)Ks + ((w*8+j) << 10));
  }
  // stage V transposed: thread = token, 8x16B loads, 64 scalar ds writes (2-way, free)
  {
    int tok = tid;
    const char* vbase = qkvB + ((size_t)(r0 + tok)*1536 + 1024 + h*64)*2;
    #pragma unroll
    for (int j=0;j<8;++j){
      bf16x8 vv = *reinterpret_cast<const bf16x8*>(vbase + (j<<4));
      #pragma unroll
      for (int e=0;e<8;++e)
        Vst[(j*8+e)*296 + tok] = (unsigned short)vv[e];
    }
  }
  // Q fragments in registers
  const int qrow = r0 + qc*64 + w*16;
  bf16x8 qf[2];
  #pragma unroll
  for (int kk=0;kk<2;++kk)
    qf[kk] = *reinterpret_cast<const bf16x8*>(qkvB + ((size_t)(qrow + l15)*1536 + h*64 + kk*32 + 8*lhi)*2);
  __syncthreads();

  // S = Q K^T  (16 token-tiles x 2 k-steps)
  f32x4 S[16];
  #pragma unroll
  for (int t=0;t<16;++t) S[t] = fzero;
  #pragma unroll
  for (int kk=0;kk<2;++kk){
    #pragma unroll
    for (int t=0;t<16;++t){
      int token = t*16 + l15;
      int off = token*128 + (((kk<<6) + (lhi<<4)) ^ ((token & 7) << 4));
      bf16x8 kf = *reinterpret_cast<const bf16x8*>((const char*)Ks + off);
      S[t] = MFMA_16x16x32(qf[kk], kf, S[t]);
    }
  }

  // softmax: row = lhi*4+i lives in 16-lane group; reduce with shfl_xor 1..8
  float M[4], L[4];
  #pragma unroll
  for (int i=0;i<4;++i){
    float m = S[0][i];
    #pragma unroll
    for (int t=1;t<16;++t) m = fmaxf(m, S[t][i]);
    #pragma unroll
    for (int d=1; d<16; d<<=1) m = fmaxf(m, __shfl_xor(m, d));
    M[i] = m;
    L[i] = 0.f;
  }
  #pragma unroll
  for (int t=0;t<16;++t){
    #pragma unroll
    for (int i=0;i<4;++i){
      float p = __expf((S[t][i] - M[i]) * 0.125f);   // scale 1/sqrt(64) folded here
      L[i] += p;
      Ps[(size_t)(w*16 + lhi*4 + i)*296 + t*16 + l15] = f2bf(p);
    }
  }
  #pragma unroll
  for (int i=0;i<4;++i){
    #pragma unroll
    for (int d=1; d<16; d<<=1) L[i] += __shfl_xor(L[i], d);
    L[i] = 1.0f / L[i];
  }
  asm volatile("s_waitcnt lgkmcnt(0)" ::: "memory");  // cross-lane P visibility (wave-local)
  __builtin_amdgcn_sched_barrier(0);

  // O = P V
  f32x4 O[4];
  #pragma unroll
  for (int dt=0;dt<4;++dt) O[dt] = fzero;
  #pragma unroll
  for (int step=0; step<8; ++step){
    bf16x8 pa = *reinterpret_cast<const bf16x8*>(&Ps[(size_t)(w*16 + l15)*296 + step*32 + 8*lhi]);
    #pragma unroll
    for (int dt=0;dt<4;++dt){
      bf16x8 vb = *reinterpret_cast<const bf16x8*>(&Vst[(dt*16 + l15)*296 + step*32 + 8*lhi]);
      O[dt] = MFMA_16x16x32(pa, vb, O[dt]);
    }
  }
  // fold 1/L, store ctx bf16
  #pragma unroll
  for (int dt=0;dt<4;++dt){
    #pragma unroll
    for (int i=0;i<4;++i){
      float v = O[dt][i] * L[i];
      int row = qrow + lhi*4 + i;
      int col = h*64 + dt*16 + l15;
      ctx[(size_t)row*512 + col] = f2bf(v);
    }
  }
}

// ---------------- launch ----------------
extern "C" void kernel_launch(void* const* d_in, const int* in_sizes, int n_in,
                              void* d_out, int out_size, void* d_ws, size_t ws_size,
                              hipStream_t stream) {
  const float* x  = (const float*)d_in[0];
  const float* Wq = (const float*)d_in[1];
  const float* Wk = (const float*)d_in[2];
  const float* Wv = (const float*)d_in[3];
  const float* Wo = (const float*)d_in[4];
  const float* bo = (const float*)d_in[5];
  float* out = (float*)d_out;

  char* ws = (char*)d_ws;
  // layout (bytes): xb 33,554,432 | qkv 100,663,296 | WqkvT 1,572,864 | WoT 524,288
  unsigned short* xb    = (unsigned short*)ws;
  unsigned short* qkv   = (unsigned short*)(ws + 33554432);
  unsigned short* WqkvT = (unsigned short*)(ws + 134217728);
  unsigned short* WoT   = (unsigned short*)(ws + 135790592);
  unsigned short* ctx   = xb;   // reuse: xb dead after QKV GEMM (stream-ordered)

  convert_x_kernel<<<2048, 256, 0, stream>>>(x, xb, 16777216/4);
  prep_weights<<<1024, 256, 0, stream>>>(Wq, Wk, Wv, Wo, WqkvT, WoT);
  // QKV: [32768,512] @ [512,1536] -> bf16 qkv
  gemm_bt<false, true><<<256*12, 256, 0, stream>>>(xb, WqkvT, nullptr, qkv, nullptr,
                                                   32768, 1536, 512, 1536);
  attn_kernel<<<4096, 256, 0, stream>>>(qkv, ctx);
  // out: [32768,512] @ [512,512] + bo -> fp32
  gemm_bt<true, false><<<256*4, 256, 0, stream>>>(ctx, WoT, out, nullptr, bo,
                                                  32768, 512, 512, 512);
}

// Round 2
// 187.921 us; speedup vs baseline: 1.3848x; 1.3848x over previous
//
#include <hip/hip_runtime.h>
#include <hip/hip_bf16.h>

typedef __attribute__((ext_vector_type(8))) short bf16x8;
typedef __attribute__((ext_vector_type(4))) float f32x4;

#define MFMA_16x16x32(a,b,c) __builtin_amdgcn_mfma_f32_16x16x32_bf16((a),(b),(c),0,0,0)

__device__ __forceinline__ unsigned short f2bf(float f){
  unsigned int u = __float_as_uint(f);
  u += 0x7FFFu + ((u >> 16) & 1u);   // RNE
  return (unsigned short)(u >> 16);
}

__device__ __forceinline__ unsigned int cvtpk_bf16(float lo, float hi){
  unsigned int r;
  asm("v_cvt_pk_bf16_f32 %0, %1, %2" : "=v"(r) : "v"(lo), "v"(hi));
  return r;
}

__device__ __forceinline__ void async16(const void* g, void* l){
  __builtin_amdgcn_global_load_lds((const __attribute__((address_space(1))) void*)g,
                                   (__attribute__((address_space(3))) void*)l,
                                   16, 0, 0);
}

// ---------------- converters ----------------
__global__ __launch_bounds__(256) void convert_x_kernel(const float* __restrict__ x,
                                                        unsigned short* __restrict__ xb, int n4){
  int idx = blockIdx.x*256 + threadIdx.x;
  int stride = gridDim.x*256;
  for (int i = idx; i < n4; i += stride){
    float4 v = reinterpret_cast<const float4*>(x)[i];
    ushort4 o;
    o.x = f2bf(v.x); o.y = f2bf(v.y); o.z = f2bf(v.z); o.w = f2bf(v.w);
    reinterpret_cast<ushort4*>(xb)[i] = o;
  }
}

__global__ __launch_bounds__(256) void prep_weights(const float* __restrict__ Wq,
                                                    const float* __restrict__ Wk,
                                                    const float* __restrict__ Wv,
                                                    const float* __restrict__ Wo,
                                                    unsigned short* __restrict__ WqkvT,
                                                    unsigned short* __restrict__ WoT){
  int idx = blockIdx.x*256 + threadIdx.x;
  int stride = gridDim.x*256;
  const int T1 = 1536*512;
  const int total = T1 + 512*512;
  for (int o = idx; o < total; o += stride){
    if (o < T1){
      int n = o >> 9, k = o & 511;
      const float* W = (n < 512) ? Wq : ((n < 1024) ? Wk : Wv);
      WqkvT[o] = f2bf(W[k*512 + (n & 511)]);
    } else {
      int o2 = o - T1;
      int n = o2 >> 9, k = o2 & 511;
      WoT[o2] = f2bf(Wo[k*512 + n]);
    }
  }
}

// ---------------- GEMM: C[M,N] = A[M,K] * Bt[N,K]^T (+bias) ----------------
template<bool BIAS, bool OUTBF16>
__global__ __launch_bounds__(256) void gemm_bt(const unsigned short* __restrict__ A,
                                               const unsigned short* __restrict__ Bt,
                                               float* __restrict__ Cf, unsigned short* __restrict__ Cb,
                                               const float* __restrict__ bias,
                                               int M, int N, int K, int ldc){
  __shared__ __attribute__((aligned(16))) unsigned short As[128*64];
  __shared__ __attribute__((aligned(16))) unsigned short Bs[128*64];
  const int tid = threadIdx.x;
  const int lane = tid & 63;
  const int w = tid >> 6;
  const int l15 = lane & 15, lhi = lane >> 4;
  const int NB = N >> 7;
  const int bm = blockIdx.x / NB;
  const int bn = blockIdx.x % NB;
  const int wr = w >> 1, wc = w & 1;
  const f32x4 fzero = {0.f,0.f,0.f,0.f};

  f32x4 acc[4][4];
  #pragma unroll
  for (int a=0;a<4;++a)
    #pragma unroll
    for (int b=0;b<4;++b) acc[a][b] = fzero;

  for (int kt = 0; kt < K; kt += 64){
    #pragma unroll
    for (int j=0;j<4;++j){
      int c = (w*4+j)*64 + lane;
      int row = c >> 3;
      int src = ((c & 7) << 4) ^ ((row & 7) << 4);   // inverse-swizzled source
      async16((const char*)(A + (size_t)(bm*128 + row)*K + kt) + src,
              (char*)As + ((w*4+j) << 10));
    }
    #pragma unroll
    for (int j=0;j<4;++j){
      int c = (w*4+j)*64 + lane;
      int row = c >> 3;
      int src = ((c & 7) << 4) ^ ((row & 7) << 4);
      async16((const char*)(Bt + (size_t)(bn*128 + row)*K + kt) + src,
              (char*)Bs + ((w*4+j) << 10));
    }
    __syncthreads();
    #pragma unroll
    for (int kk=0;kk<2;++kk){
      bf16x8 af[4], bfr[4];
      #pragma unroll
      for (int mi=0;mi<4;++mi){
        int m = wr*64 + mi*16 + l15;
        int off = m*128 + (((kk<<6) + (lhi<<4)) ^ ((m & 7) << 4));
        af[mi] = *reinterpret_cast<const bf16x8*>((const char*)As + off);
      }
      #pragma unroll
      for (int ni=0;ni<4;++ni){
        int n = wc*64 + ni*16 + l15;
        int off = n*128 + (((kk<<6) + (lhi<<4)) ^ ((n & 7) << 4));
        bfr[ni] = *reinterpret_cast<const bf16x8*>((const char*)Bs + off);
      }
      #pragma unroll
      for (int mi=0;mi<4;++mi)
        #pragma unroll
        for (int ni=0;ni<4;++ni)
          acc[mi][ni] = MFMA_16x16x32(af[mi], bfr[ni], acc[mi][ni]);
    }
    __syncthreads();
  }
  #pragma unroll
  for (int mi=0;mi<4;++mi){
    int r = bm*128 + wr*64 + mi*16 + lhi*4;
    #pragma unroll
    for (int ni=0;ni<4;++ni){
      int cc = bn*128 + wc*64 + ni*16 + l15;
      float bv = 0.f;
      if (BIAS) bv = bias[cc];
      #pragma unroll
      for (int i=0;i<4;++i){
        float v = acc[mi][ni][i] + bv;
        if (OUTBF16) Cb[(size_t)(r+i)*ldc + cc] = f2bf(v);
        else         Cf[(size_t)(r+i)*ldc + cc] = v;
      }
    }
  }
}

// ---------------- attention: one block per (b,t,h), 256 thr, 4 waves ----------------
// Swapped QK^T (S^T = mfma(K,Q)): lane l15 owns full 256-token score row of one
// q-row -> in-register softmax (2 shfl_xor) -> cvt_pk + shfl redistribution -> PV.
__global__ __launch_bounds__(256) void attn_kernel(const unsigned short* __restrict__ qkv,
                                                   unsigned short* __restrict__ ctx){
  __shared__ __attribute__((aligned(16))) unsigned short Ks[256*64];   // 32 KB, XOR-swizzled rows
  __shared__ __attribute__((aligned(16))) unsigned short Vst[64*264];  // 33 KB, [d][tok] padded

  const int bid = blockIdx.x;            // 1024 = (b*t)*8
  const int h = bid & 7, bt = bid >> 3;
  const int r0 = bt << 8;
  const int tid = threadIdx.x;
  const int lane = tid & 63, w = tid >> 6;
  const int l15 = lane & 15, lhi = lane >> 4;
  const char* qkvB = (const char*)qkv;
  const f32x4 fzero = {0.f,0.f,0.f,0.f};

  // Prefetch Q fragments for all 4 subtiles (B operand: lane(l15,lhi): n=q, k=kk*32+lhi*8)
  bf16x8 qf[4][2];
  #pragma unroll
  for (int st=0; st<4; ++st){
    int q0 = w*64 + st*16;
    #pragma unroll
    for (int kk=0; kk<2; ++kk)
      qf[st][kk] = *reinterpret_cast<const bf16x8*>(
          qkvB + ((size_t)(r0 + q0 + l15)*1536 + h*64 + kk*32 + lhi*8)*2);
  }

  // Stage K: 32 pages x 1024B, pre-swizzled global source -> linear LDS dest
  #pragma unroll
  for (int j=0;j<8;++j){
    int c = (w*8+j)*64 + lane;
    int tok = c >> 3;
    int src = ((c & 7) << 4) ^ ((tok & 7) << 4);
    async16(qkvB + ((size_t)(r0 + tok)*1536 + 512 + h*64)*2 + src,
            (char*)Ks + ((w*8+j) << 10));
  }
  // Stage V transposed: thread = token, 8x16B loads, 64 scalar ds writes (2-way, free)
  {
    const char* vbase = qkvB + ((size_t)(r0 + tid)*1536 + 1024 + h*64)*2;
    #pragma unroll
    for (int j=0;j<8;++j){
      bf16x8 vv = *reinterpret_cast<const bf16x8*>(vbase + (j<<4));
      #pragma unroll
      for (int e=0;e<8;++e)
        Vst[(j*8+e)*264 + tid] = (unsigned short)vv[e];
    }
  }
  __syncthreads();

  const int ga2 = (lhi & 1) << 1;        // source group pair for P redistribution
  const int lA = l15 + (ga2 << 4);
  const int lB = lA + 16;
  const bool odd = (lhi >> 1) != 0;

  #pragma unroll
  for (int st=0; st<4; ++st){
    const int q0 = w*64 + st*16;

    // S^T = K · Q^T : lane(l15,lhi) holds S[tok = t*16+lhi*4+i][qrow = q0+l15]
    f32x4 S[16];
    #pragma unroll
    for (int t=0;t<16;++t) S[t] = fzero;
    #pragma unroll
    for (int kk=0;kk<2;++kk){
      #pragma unroll
      for (int t=0;t<16;++t){
        int tok = t*16 + l15;
        int off = tok*128 + (((kk<<6) + (lhi<<4)) ^ ((tok & 7) << 4));
        bf16x8 kf = *reinterpret_cast<const bf16x8*>((const char*)Ks + off);
        S[t] = MFMA_16x16x32(kf, qf[st][kk], S[t]);
      }
    }

    // in-register softmax over the lane's 64 values + cross-group reduce
    float m = S[0][0];
    #pragma unroll
    for (int t=0;t<16;++t)
      #pragma unroll
      for (int i=0;i<4;++i) m = fmaxf(m, S[t][i]);
    m = fmaxf(m, __shfl_xor(m, 16));
    m = fmaxf(m, __shfl_xor(m, 32));

    float l = 0.f;
    unsigned int P2[32];
    #pragma unroll
    for (int t=0;t<16;++t){
      float p0 = __expf((S[t][0] - m) * 0.125f);
      float p1 = __expf((S[t][1] - m) * 0.125f);
      float p2 = __expf((S[t][2] - m) * 0.125f);
      float p3 = __expf((S[t][3] - m) * 0.125f);
      l += (p0 + p1) + (p2 + p3);
      P2[2*t]   = cvtpk_bf16(p0, p1);
      P2[2*t+1] = cvtpk_bf16(p2, p3);
    }
    l += __shfl_xor(l, 16);
    l += __shfl_xor(l, 32);
    float rl = 1.0f / l;

    // O = P V : redistribute P2 to A-frag layout per 32-token step via shfl
    f32x4 O[4];
    #pragma unroll
    for (int dt=0;dt<4;++dt) O[dt] = fzero;
    #pragma unroll
    for (int s=0;s<8;++s){
      unsigned int a0e = __shfl((int)P2[4*s+0], lA), a0o = __shfl((int)P2[4*s+2], lA);
      unsigned int a1e = __shfl((int)P2[4*s+1], lA), a1o = __shfl((int)P2[4*s+3], lA);
      unsigned int b0e = __shfl((int)P2[4*s+0], lB), b0o = __shfl((int)P2[4*s+2], lB);
      unsigned int b1e = __shfl((int)P2[4*s+1], lB), b1o = __shfl((int)P2[4*s+3], lB);
      unsigned int u0 = odd ? a0o : a0e;
      unsigned int u1 = odd ? a1o : a1e;
      unsigned int u2 = odd ? b0o : b0e;
      unsigned int u3 = odd ? b1o : b1e;
      bf16x8 pa;
      reinterpret_cast<unsigned int*>(&pa)[0] = u0;
      reinterpret_cast<unsigned int*>(&pa)[1] = u1;
      reinterpret_cast<unsigned int*>(&pa)[2] = u2;
      reinterpret_cast<unsigned int*>(&pa)[3] = u3;
      #pragma unroll
      for (int dt=0;dt<4;++dt){
        bf16x8 vb = *reinterpret_cast<const bf16x8*>(&Vst[(dt*16 + l15)*264 + s*32 + 8*lhi]);
        O[dt] = MFMA_16x16x32(pa, vb, O[dt]);
      }
    }

    // epilogue: rows q0+lhi*4+i need 1/L of those rows (held per-l15) -> 4 shfl
    float rl4[4];
    #pragma unroll
    for (int i=0;i<4;++i) rl4[i] = __shfl(rl, lhi*4 + i);
    #pragma unroll
    for (int dt=0;dt<4;++dt){
      int col = h*64 + dt*16 + l15;
      #pragma unroll
      for (int i=0;i<4;++i){
        int row = r0 + q0 + lhi*4 + i;
        ctx[(size_t)row*512 + col] = f2bf(O[dt][i] * rl4[i]);
      }
    }
  }
}

// ---------------- launch ----------------
extern "C" void kernel_launch(void* const* d_in, const int* in_sizes, int n_in,
                              void* d_out, int out_size, void* d_ws, size_t ws_size,
                              hipStream_t stream) {
  const float* x  = (const float*)d_in[0];
  const float* Wq = (const float*)d_in[1];
  const float* Wk = (const float*)d_in[2];
  const float* Wv = (const float*)d_in[3];
  const float* Wo = (const float*)d_in[4];
  const float* bo = (const float*)d_in[5];
  float* out = (float*)d_out;

  char* ws = (char*)d_ws;
  unsigned short* xb    = (unsigned short*)ws;
  unsigned short* qkv   = (unsigned short*)(ws + 33554432);
  unsigned short* WqkvT = (unsigned short*)(ws + 134217728);
  unsigned short* WoT   = (unsigned short*)(ws + 135790592);
  unsigned short* ctx   = xb;   // reuse: xb dead after QKV GEMM (stream-ordered)

  convert_x_kernel<<<2048, 256, 0, stream>>>(x, xb, 16777216/4);
  prep_weights<<<1024, 256, 0, stream>>>(Wq, Wk, Wv, Wo, WqkvT, WoT);
  gemm_bt<false, true><<<256*12, 256, 0, stream>>>(xb, WqkvT, nullptr, qkv, nullptr,
                                                   32768, 1536, 512, 1536);
  attn_kernel<<<1024, 256, 0, stream>>>(qkv, ctx);
  gemm_bt<true, false><<<256*4, 256, 0, stream>>>(ctx, WoT, out, nullptr, bo,
                                                  32768, 512, 512, 512);
}

// Round 3
// 168.416 us; speedup vs baseline: 1.5452x; 1.1158x over previous
//
#include <hip/hip_runtime.h>
#include <hip/hip_bf16.h>

typedef __attribute__((ext_vector_type(8))) short bf16x8;
typedef __attribute__((ext_vector_type(4))) float f32x4;

#define MFMA_16x16x32(a,b,c) __builtin_amdgcn_mfma_f32_16x16x32_bf16((a),(b),(c),0,0,0)

__device__ __forceinline__ unsigned short f2bf(float f){
  unsigned int u = __float_as_uint(f);
  u += 0x7FFFu + ((u >> 16) & 1u);   // RNE
  return (unsigned short)(u >> 16);
}

__device__ __forceinline__ unsigned int cvtpk_bf16(float lo, float hi){
  unsigned int r;
  asm("v_cvt_pk_bf16_f32 %0, %1, %2" : "=v"(r) : "v"(lo), "v"(hi));
  return r;
}

__device__ __forceinline__ void async16(const void* g, void* l){
  __builtin_amdgcn_global_load_lds((const __attribute__((address_space(1))) void*)g,
                                   (__attribute__((address_space(3))) void*)l,
                                   16, 0, 0);
}

#define FENCE asm volatile("" ::: "memory")
#define BARR  do{ FENCE; __builtin_amdgcn_s_barrier(); FENCE; }while(0)

// ---------------- converters ----------------
__global__ __launch_bounds__(256) void convert_x_kernel(const float* __restrict__ x,
                                                        unsigned short* __restrict__ xb, int n4){
  int idx = blockIdx.x*256 + threadIdx.x;
  int stride = gridDim.x*256;
  for (int i = idx; i < n4; i += stride){
    float4 v = reinterpret_cast<const float4*>(x)[i];
    ushort4 o;
    o.x = f2bf(v.x); o.y = f2bf(v.y); o.z = f2bf(v.z); o.w = f2bf(v.w);
    reinterpret_cast<ushort4*>(xb)[i] = o;
  }
}

__global__ __launch_bounds__(256) void prep_weights(const float* __restrict__ Wq,
                                                    const float* __restrict__ Wk,
                                                    const float* __restrict__ Wv,
                                                    const float* __restrict__ Wo,
                                                    unsigned short* __restrict__ WqkvT,
                                                    unsigned short* __restrict__ WoT){
  int idx = blockIdx.x*256 + threadIdx.x;
  int stride = gridDim.x*256;
  const int T1 = 1536*512;
  const int total = T1 + 512*512;
  for (int o = idx; o < total; o += stride){
    if (o < T1){
      int n = o >> 9, k = o & 511;
      const float* W = (n < 512) ? Wq : ((n < 1024) ? Wk : Wv);
      WqkvT[o] = f2bf(W[k*512 + (n & 511)]);
    } else {
      int o2 = o - T1;
      int n = o2 >> 9, k = o2 & 511;
      WoT[o2] = f2bf(Wo[k*512 + n]);
    }
  }
}

// ---------------- 8-phase 256x256 GEMM: C[M,N] = A[M,K] * Bt[N,K]^T (+bias) ----------------
// 512 thr / 8 waves (2M x 4N); BK=64; 4 phases per K-tile, one C-quadrant each;
// counted vmcnt(4) per tile (T3+T4); setprio around MFMA (T5); st-swizzled LDS (T2);
// XCD-bijective grid swizzle (T1). grid = 128*NB blocks, gridDim%8==0.
template<bool BIAS, bool OUTBF16>
__global__ __launch_bounds__(512, 2) void gemm8(const unsigned short* __restrict__ A,
                                                const unsigned short* __restrict__ Bt,
                                                float* __restrict__ Cf, unsigned short* __restrict__ Cb,
                                                const float* __restrict__ bias,
                                                int K, int NB, int ldc){
  __shared__ __attribute__((aligned(16))) char ldsA[2][32768];
  __shared__ __attribute__((aligned(16))) char ldsB[2][32768];
  const int tid = threadIdx.x;
  const int lane = tid & 63, w = tid >> 6;
  const int wr = w >> 2, wc = w & 3;
  const int l15 = lane & 15, lhi = lane >> 4;
  const int xorv = (l15 & 7) << 4;

  const int cpx = gridDim.x >> 3;
  const int bid = (blockIdx.x & 7) * cpx + (blockIdx.x >> 3);
  const int bm = bid / NB, bn = bid % NB;

  // staging per-thread constants: idx j*512+tid covers a 128x64 half (16KB, 2 issues)
  const int row0 = tid >> 3;                                  // 0..63
  const int srcb = ((tid & 7) << 4) ^ ((row0 & 7) << 4);      // pre-swizzled source byte
  const size_t rK2 = (size_t)K * 2;
  const char* Ab = (const char*)(A + (size_t)(bm*256 + row0) * K) + srcb;
  const char* Bb = (const char*)(Bt + (size_t)(bn*256 + row0) * K) + srcb;

#define STG_A(p,h,kt) do{ \
    async16(Ab + (size_t)((h)*128)*rK2      + (size_t)(kt)*2, ldsA[p] + (h)*16384 +        w*1024); \
    async16(Ab + (size_t)((h)*128 + 64)*rK2 + (size_t)(kt)*2, ldsA[p] + (h)*16384 + 8192 + w*1024); }while(0)
#define STG_B(p,h,kt) do{ \
    async16(Bb + (size_t)((h)*128)*rK2      + (size_t)(kt)*2, ldsB[p] + (h)*16384 +        w*1024); \
    async16(Bb + (size_t)((h)*128 + 64)*rK2 + (size_t)(kt)*2, ldsB[p] + (h)*16384 + 8192 + w*1024); }while(0)

#define LDAF(p, mh) do{ _Pragma("unroll") for (int f=0;f<4;++f){ \
    const char* base_ = ldsA[p] + (wr*128 + ((mh)*4+f)*16 + l15)*128; \
    af[f][0] = *reinterpret_cast<const bf16x8*>(base_ + (((lhi<<4))      ^ xorv)); \
    af[f][1] = *reinterpret_cast<const bf16x8*>(base_ + ((64 + (lhi<<4)) ^ xorv)); } }while(0)
#define LDBF(dst, p, nh) do{ _Pragma("unroll") for (int n2=0;n2<2;++n2){ \
    const char* base_ = ldsB[p] + (wc*64 + ((nh)*2+n2)*16 + l15)*128; \
    dst[n2][0] = *reinterpret_cast<const bf16x8*>(base_ + (((lhi<<4))      ^ xorv)); \
    dst[n2][1] = *reinterpret_cast<const bf16x8*>(base_ + ((64 + (lhi<<4)) ^ xorv)); } }while(0)
#define MFQ(mh, nh, B_) do{ _Pragma("unroll") for (int f=0;f<4;++f) \
    _Pragma("unroll") for (int n2=0;n2<2;++n2) \
    _Pragma("unroll") for (int kk=0;kk<2;++kk) \
      acc[(mh)*4+f][(nh)*2+n2] = MFMA_16x16x32(af[f][kk], B_[n2][kk], acc[(mh)*4+f][(nh)*2+n2]); }while(0)

  f32x4 acc[8][4];
  const f32x4 fzero = {0.f,0.f,0.f,0.f};
  #pragma unroll
  for (int i=0;i<8;++i)
    #pragma unroll
    for (int j=0;j<4;++j) acc[i][j] = fzero;
  bf16x8 af[4][2], bf0[2][2], bfc[2][2];
  const int nt = K >> 6;

  // prologue: tile0 complete + tile1 B-halves; leaves 4 loads in flight
  STG_B(0,0,0);  STG_B(0,1,0);  STG_A(0,0,0);  STG_A(0,1,0);
  STG_B(1,0,64); STG_B(1,1,64);
  asm volatile("s_waitcnt vmcnt(4)" ::: "memory");
  __builtin_amdgcn_s_barrier(); FENCE;

  for (int t = 0; t < nt; ++t){
    const int p = t & 1, o = p ^ 1;
    const int kt1 = (t+1) << 6, kt2 = (t+2) << 6;
    // Phase A: quadrant (0,0); stage A0(t+1)  [region free since tile t-1 phase C]
    LDAF(p, 0); LDBF(bf0, p, 0);
    if (t+1 < nt) STG_A(o, 0, kt1);
    BARR;
    __builtin_amdgcn_s_setprio(1); MFQ(0, 0, bf0); __builtin_amdgcn_s_setprio(0);
    BARR;
    // Phase B: quadrant (0,1); stage A1(t+1)
    LDBF(bfc, p, 1);
    if (t+1 < nt) STG_A(o, 1, kt1);
    BARR;
    __builtin_amdgcn_s_setprio(1); MFQ(0, 1, bfc); __builtin_amdgcn_s_setprio(0);
    BARR;
    // Phase C: quadrant (1,1); stage B0(t+2)  [B0(t) reads drained end of phase B]
    LDAF(p, 1);
    if (t+2 < nt) STG_B(p, 0, kt2);
    BARR;
    __builtin_amdgcn_s_setprio(1); MFQ(1, 1, bfc); __builtin_amdgcn_s_setprio(0);
    BARR;
    // Phase D: quadrant (1,0); stage B1(t+2); end-of-tile counted wait
    if (t+2 < nt) STG_B(p, 1, kt2);
    BARR;
    __builtin_amdgcn_s_setprio(1); MFQ(1, 0, bf0); __builtin_amdgcn_s_setprio(0);
    if (t+1 < nt){
      if (t+2 < nt) asm volatile("s_waitcnt vmcnt(4)" ::: "memory");
      else          asm volatile("s_waitcnt vmcnt(0)" ::: "memory");
      __builtin_amdgcn_s_barrier(); FENCE;
    }
  }

  // epilogue
  #pragma unroll
  for (int mi=0;mi<8;++mi){
    const int r = bm*256 + wr*128 + mi*16 + lhi*4;
    #pragma unroll
    for (int ni=0;ni<4;++ni){
      const int cc = bn*256 + wc*64 + ni*16 + l15;
      float bv = 0.f;
      if (BIAS) bv = bias[cc];
      #pragma unroll
      for (int i=0;i<4;++i){
        float v = acc[mi][ni][i] + bv;
        if (OUTBF16) Cb[(size_t)(r+i)*ldc + cc] = f2bf(v);
        else         Cf[(size_t)(r+i)*ldc + cc] = v;
      }
    }
  }
#undef STG_A
#undef STG_B
#undef LDAF
#undef LDBF
#undef MFQ
}

// ---------------- attention: one block per (b,t,h), 256 thr, 4 waves ----------------
__global__ __launch_bounds__(256) void attn_kernel(const unsigned short* __restrict__ qkv,
                                                   unsigned short* __restrict__ ctx){
  __shared__ __attribute__((aligned(16))) unsigned short Ks[256*64];   // 32 KB, XOR-swizzled rows
  __shared__ __attribute__((aligned(16))) unsigned short Vst[64*264];  // 33 KB, [d][tok] padded

  const int bid = blockIdx.x;            // 1024 = (b*t)*8
  const int h = bid & 7, bt = bid >> 3;
  const int r0 = bt << 8;
  const int tid = threadIdx.x;
  const int lane = tid & 63, w = tid >> 6;
  const int l15 = lane & 15, lhi = lane >> 4;
  const char* qkvB = (const char*)qkv;
  const f32x4 fzero = {0.f,0.f,0.f,0.f};

  bf16x8 qf[4][2];
  #pragma unroll
  for (int st=0; st<4; ++st){
    int q0 = w*64 + st*16;
    #pragma unroll
    for (int kk=0; kk<2; ++kk)
      qf[st][kk] = *reinterpret_cast<const bf16x8*>(
          qkvB + ((size_t)(r0 + q0 + l15)*1536 + h*64 + kk*32 + lhi*8)*2);
  }

  #pragma unroll
  for (int j=0;j<8;++j){
    int c = (w*8+j)*64 + lane;
    int tok = c >> 3;
    int src = ((c & 7) << 4) ^ ((tok & 7) << 4);
    async16(qkvB + ((size_t)(r0 + tok)*1536 + 512 + h*64)*2 + src,
            (char*)Ks + ((w*8+j) << 10));
  }
  {
    const char* vbase = qkvB + ((size_t)(r0 + tid)*1536 + 1024 + h*64)*2;
    #pragma unroll
    for (int j=0;j<8;++j){
      bf16x8 vv = *reinterpret_cast<const bf16x8*>(vbase + (j<<4));
      #pragma unroll
      for (int e=0;e<8;++e)
        Vst[(j*8+e)*264 + tid] = (unsigned short)vv[e];
    }
  }
  __syncthreads();

  const int ga2 = (lhi & 1) << 1;
  const int lA = l15 + (ga2 << 4);
  const int lB = lA + 16;
  const bool odd = (lhi >> 1) != 0;

  #pragma unroll
  for (int st=0; st<4; ++st){
    const int q0 = w*64 + st*16;

    f32x4 S[16];
    #pragma unroll
    for (int t=0;t<16;++t) S[t] = fzero;
    #pragma unroll
    for (int kk=0;kk<2;++kk){
      #pragma unroll
      for (int t=0;t<16;++t){
        int tok = t*16 + l15;
        int off = tok*128 + (((kk<<6) + (lhi<<4)) ^ ((tok & 7) << 4));
        bf16x8 kf = *reinterpret_cast<const bf16x8*>((const char*)Ks + off);
        S[t] = MFMA_16x16x32(kf, qf[st][kk], S[t]);
      }
    }

    float m = S[0][0];
    #pragma unroll
    for (int t=0;t<16;++t)
      #pragma unroll
      for (int i=0;i<4;++i) m = fmaxf(m, S[t][i]);
    m = fmaxf(m, __shfl_xor(m, 16));
    m = fmaxf(m, __shfl_xor(m, 32));

    float l = 0.f;
    unsigned int P2[32];
    #pragma unroll
    for (int t=0;t<16;++t){
      float p0 = __expf((S[t][0] - m) * 0.125f);
      float p1 = __expf((S[t][1] - m) * 0.125f);
      float p2 = __expf((S[t][2] - m) * 0.125f);
      float p3 = __expf((S[t][3] - m) * 0.125f);
      l += (p0 + p1) + (p2 + p3);
      P2[2*t]   = cvtpk_bf16(p0, p1);
      P2[2*t+1] = cvtpk_bf16(p2, p3);
    }
    l += __shfl_xor(l, 16);
    l += __shfl_xor(l, 32);
    float rl = 1.0f / l;

    f32x4 O[4];
    #pragma unroll
    for (int dt=0;dt<4;++dt) O[dt] = fzero;
    #pragma unroll
    for (int s=0;s<8;++s){
      unsigned int a0e = __shfl((int)P2[4*s+0], lA), a0o = __shfl((int)P2[4*s+2], lA);
      unsigned int a1e = __shfl((int)P2[4*s+1], lA), a1o = __shfl((int)P2[4*s+3], lA);
      unsigned int b0e = __shfl((int)P2[4*s+0], lB), b0o = __shfl((int)P2[4*s+2], lB);
      unsigned int b1e = __shfl((int)P2[4*s+1], lB), b1o = __shfl((int)P2[4*s+3], lB);
      unsigned int u0 = odd ? a0o : a0e;
      unsigned int u1 = odd ? a1o : a1e;
      unsigned int u2 = odd ? b0o : b0e;
      unsigned int u3 = odd ? b1o : b1e;
      bf16x8 pa;
      reinterpret_cast<unsigned int*>(&pa)[0] = u0;
      reinterpret_cast<unsigned int*>(&pa)[1] = u1;
      reinterpret_cast<unsigned int*>(&pa)[2] = u2;
      reinterpret_cast<unsigned int*>(&pa)[3] = u3;
      #pragma unroll
      for (int dt=0;dt<4;++dt){
        bf16x8 vb = *reinterpret_cast<const bf16x8*>(&Vst[(dt*16 + l15)*264 + s*32 + 8*lhi]);
        O[dt] = MFMA_16x16x32(pa, vb, O[dt]);
      }
    }

    float rl4[4];
    #pragma unroll
    for (int i=0;i<4;++i) rl4[i] = __shfl(rl, lhi*4 + i);
    #pragma unroll
    for (int dt=0;dt<4;++dt){
      int col = h*64 + dt*16 + l15;
      #pragma unroll
      for (int i=0;i<4;++i){
        int row = r0 + q0 + lhi*4 + i;
        ctx[(size_t)row*512 + col] = f2bf(O[dt][i] * rl4[i]);
      }
    }
  }
}

// ---------------- launch ----------------
extern "C" void kernel_launch(void* const* d_in, const int* in_sizes, int n_in,
                              void* d_out, int out_size, void* d_ws, size_t ws_size,
                              hipStream_t stream) {
  const float* x  = (const float*)d_in[0];
  const float* Wq = (const float*)d_in[1];
  const float* Wk = (const float*)d_in[2];
  const float* Wv = (const float*)d_in[3];
  const float* Wo = (const float*)d_in[4];
  const float* bo = (const float*)d_in[5];
  float* out = (float*)d_out;

  char* ws = (char*)d_ws;
  unsigned short* xb    = (unsigned short*)ws;
  unsigned short* qkv   = (unsigned short*)(ws + 33554432);
  unsigned short* WqkvT = (unsigned short*)(ws + 134217728);
  unsigned short* WoT   = (unsigned short*)(ws + 135790592);
  unsigned short* ctx   = xb;   // reuse: xb dead after QKV GEMM (stream-ordered)

  convert_x_kernel<<<2048, 256, 0, stream>>>(x, xb, 16777216/4);
  prep_weights<<<1024, 256, 0, stream>>>(Wq, Wk, Wv, Wo, WqkvT, WoT);
  // QKV: [32768,512] @ [512,1536] -> bf16 qkv ; grid 128*6
  gemm8<false, true><<<768, 512, 0, stream>>>(xb, WqkvT, nullptr, qkv, nullptr, 512, 6, 1536);
  attn_kernel<<<1024, 256, 0, stream>>>(qkv, ctx);
  // out: [32768,512] @ [512,512] + bo -> fp32 ; grid 128*2
  gemm8<true, false><<<256, 512, 0, stream>>>(ctx, WoT, out, nullptr, bo, 512, 2, 512);
}